// Round 2
// baseline (13118.710 us; speedup 1.0000x reference)
//
#include <hip/hip_runtime.h>
#include <hip/hip_bf16.h>

#define L_   8
#define H_   16
#define E_   1024
#define V_   32000
#define T_   1024
#define B_   2
#define HS_  64
#define DFF_ 4096
#define MROWS (B_*T_)   // 2048

// ---------------------------------------------------------------------------
// Embedding: x[b*T+t, e] = tok_emb[idx[b,t], e] + pos_emb[t, e]
// ---------------------------------------------------------------------------
__global__ __launch_bounds__(256) void embed_k(const int* __restrict__ idx,
                                               const float* __restrict__ tok,
                                               const float* __restrict__ pos,
                                               float* __restrict__ x)
{
    const int bt = blockIdx.x;          // 0..2047
    const int t  = bt & (T_ - 1);
    const int token = idx[bt];
    const int e = threadIdx.x * 4;
    float4 tv = *(const float4*)(tok + (size_t)token * E_ + e);
    float4 pv = *(const float4*)(pos + (size_t)t * E_ + e);
    float4 o = make_float4(tv.x + pv.x, tv.y + pv.y, tv.z + pv.z, tv.w + pv.w);
    *(float4*)(x + (size_t)bt * E_ + e) = o;
}

// ---------------------------------------------------------------------------
// LayerNorm: one block per row (E=1024, 256 threads x 4 elements)
// ---------------------------------------------------------------------------
__global__ __launch_bounds__(256) void ln_k(const float* __restrict__ x,
                                            const float* __restrict__ g,
                                            const float* __restrict__ b,
                                            float* __restrict__ out)
{
    const int row = blockIdx.x;
    const int tid = threadIdx.x;
    const float* xr = x + (size_t)row * E_;
    float4 v = ((const float4*)xr)[tid];
    float s  = v.x + v.y + v.z + v.w;
    float ss = v.x*v.x + v.y*v.y + v.z*v.z + v.w*v.w;
#pragma unroll
    for (int off = 32; off > 0; off >>= 1) {
        s  += __shfl_down(s,  off);
        ss += __shfl_down(ss, off);
    }
    __shared__ float sm[4], sm2[4];
    if ((tid & 63) == 0) { sm[tid >> 6] = s; sm2[tid >> 6] = ss; }
    __syncthreads();
    s  = sm[0] + sm[1] + sm[2] + sm[3];
    ss = sm2[0] + sm2[1] + sm2[2] + sm2[3];
    const float mean = s * (1.f / E_);
    const float var  = ss * (1.f / E_) - mean * mean;
    const float rstd = rsqrtf(var + 1e-5f);
    float4 gv = ((const float4*)g)[tid];
    float4 bv = ((const float4*)b)[tid];
    float4 o;
    o.x = (v.x - mean) * rstd * gv.x + bv.x;
    o.y = (v.y - mean) * rstd * gv.y + bv.y;
    o.z = (v.z - mean) * rstd * gv.z + bv.z;
    o.w = (v.w - mean) * rstd * gv.w + bv.w;
    ((float4*)(out + (size_t)row * E_))[tid] = o;
}

// ---------------------------------------------------------------------------
// Generic tiled GEMM, fp32.
//   C[m,n] = sum_k A[m,k] * B[k,n]       (BT=false, B row-major [K,N])
//   C[m,n] = sum_k A[m,k] * B[n,k]       (BT=true,  B row-major [N,K])
// Epilogue: optional bias[n], fp32 residual[m,n] add, relu.
// 64x64 tile, 256 threads, 4x4 microtile, BK=16.
// ---------------------------------------------------------------------------
template<bool BT, bool BIAS, bool RELU, bool RES>
__global__ __launch_bounds__(256) void gemm_k(const float* __restrict__ A,
                                              const float* __restrict__ Bw,
                                              const float* __restrict__ bias,
                                              const float* __restrict__ res,
                                              float* __restrict__ C,
                                              int M, int N, int K)
{
    __shared__ float As[16][64];   // [k][m]
    __shared__ float Bs[16][64];   // [k][n]
    const int tid = threadIdx.x;
    const int n0 = blockIdx.x * 64, m0 = blockIdx.y * 64;
    const int tx = tid & 15, ty = tid >> 4;
    const int ar = tid >> 2, ak = (tid & 3) * 4;   // A loader: row 0..63, k {0,4,8,12}
    const int bk = tid >> 4, bn = (tid & 15) * 4;  // B loader (no-T): k 0..15, n*4

    float acc[4][4] = {};

    for (int k0 = 0; k0 < K; k0 += 16) {
        float4 a4 = *(const float4*)(A + (size_t)(m0 + ar) * K + (k0 + ak));
        As[ak + 0][ar] = a4.x; As[ak + 1][ar] = a4.y;
        As[ak + 2][ar] = a4.z; As[ak + 3][ar] = a4.w;
        if (!BT) {
            float4 b4 = *(const float4*)(Bw + (size_t)(k0 + bk) * N + (n0 + bn));
            *(float4*)&Bs[bk][bn] = b4;
        } else {
            float4 b4 = *(const float4*)(Bw + (size_t)(n0 + ar) * K + (k0 + ak));
            Bs[ak + 0][ar] = b4.x; Bs[ak + 1][ar] = b4.y;
            Bs[ak + 2][ar] = b4.z; Bs[ak + 3][ar] = b4.w;
        }
        __syncthreads();
#pragma unroll
        for (int kk = 0; kk < 16; ++kk) {
            float4 a4v = *(const float4*)&As[kk][ty * 4];
            float4 b4v = *(const float4*)&Bs[kk][tx * 4];
            float a[4] = {a4v.x, a4v.y, a4v.z, a4v.w};
            float b[4] = {b4v.x, b4v.y, b4v.z, b4v.w};
#pragma unroll
            for (int i = 0; i < 4; ++i)
#pragma unroll
                for (int j = 0; j < 4; ++j)
                    acc[i][j] = fmaf(a[i], b[j], acc[i][j]);
        }
        __syncthreads();
    }

#pragma unroll
    for (int i = 0; i < 4; ++i) {
        const int m = m0 + ty * 4 + i;
#pragma unroll
        for (int j = 0; j < 4; ++j) {
            const int n = n0 + tx * 4 + j;
            float v = acc[i][j];
            if (BIAS) v += bias[n];
            if (RES)  v += res[(size_t)m * N + n];
            if (RELU) v = fmaxf(v, 0.f);
            C[(size_t)m * N + n] = v;
        }
    }
}

// ---------------------------------------------------------------------------
// Flash attention (causal), fp32. One block per (b, h, q-tile of 64 rows).
// q/k/v/o layout: [B*T, E] with head h occupying columns h*64..h*64+63.
// ---------------------------------------------------------------------------
__global__ __launch_bounds__(256) void attn_k(const float* __restrict__ q,
                                              const float* __restrict__ k,
                                              const float* __restrict__ v,
                                              float* __restrict__ o)
{
    const int qt = blockIdx.x;   // 0..15
    const int h  = blockIdx.y;   // 0..15
    const int b  = blockIdx.z;   // 0..1
    const int tid = threadIdx.x;

    __shared__ float Qs[64][65], Ks[64][65], Vs[64][65], Ss[64][65];
    __shared__ float m_i[64], l_i[64], alph[64];

    const int r  = tid >> 2;          // owned row 0..63
    const int c0 = (tid & 3) * 16;    // owned 16-col slice
    const size_t qbase = ((size_t)(b * T_ + qt * 64)) * E_ + h * HS_;

    for (int i2 = tid; i2 < 64 * 64; i2 += 256) {
        int rr = i2 >> 6, d = i2 & 63;
        Qs[rr][d] = q[qbase + (size_t)rr * E_ + d];
    }
    if (tid < 64) { m_i[tid] = -1e30f; l_i[tid] = 0.f; }
    float O[16];
#pragma unroll
    for (int c = 0; c < 16; ++c) O[c] = 0.f;

    const int qglob = qt * 64 + r;

    for (int kt = 0; kt <= qt; ++kt) {
        __syncthreads();   // Q/init visible; prev iteration's K/V consumers done
        const size_t kbase = ((size_t)(b * T_ + kt * 64)) * E_ + h * HS_;
        for (int i2 = tid; i2 < 64 * 64; i2 += 256) {
            int j = i2 >> 6, d = i2 & 63;
            Ks[j][d] = k[kbase + (size_t)j * E_ + d];
            Vs[j][d] = v[kbase + (size_t)j * E_ + d];
        }
        __syncthreads();

        // S tile: this thread computes S[r][c0..c0+15]
#pragma unroll 1
        for (int jj = 0; jj < 16; ++jj) {
            const int j = c0 + jj;
            float s = 0.f;
#pragma unroll
            for (int d = 0; d < 64; ++d) s = fmaf(Qs[r][d], Ks[j][d], s);
            const int jg = kt * 64 + j;
            Ss[r][j] = (jg <= qglob) ? s * 0.125f : -1e30f;
        }
        __syncthreads();

        // online softmax row pass
        if (tid < 64) {
            float tm = -1e30f;
            for (int j = 0; j < 64; ++j) tm = fmaxf(tm, Ss[tid][j]);
            const float mn = fmaxf(m_i[tid], tm);
            const float al = __expf(m_i[tid] - mn);
            float sum = 0.f;
            for (int j = 0; j < 64; ++j) {
                float p = __expf(Ss[tid][j] - mn);
                Ss[tid][j] = p;
                sum += p;
            }
            l_i[tid]  = l_i[tid] * al + sum;
            m_i[tid]  = mn;
            alph[tid] = al;
        }
        __syncthreads();

        // O = O*alpha + P @ V
        const float al = alph[r];
#pragma unroll
        for (int c = 0; c < 16; ++c) O[c] *= al;
#pragma unroll 1
        for (int j = 0; j < 64; ++j) {
            const float p = Ss[r][j];
#pragma unroll
            for (int c = 0; c < 16; ++c) O[c] = fmaf(p, Vs[j][c0 + c], O[c]);
        }
    }

    const float inv = 1.f / l_i[r];
#pragma unroll
    for (int c = 0; c < 16; ++c)
        o[qbase + (size_t)r * E_ + c0 + c] = O[c] * inv;
}

// ---------------------------------------------------------------------------
// Launch
// ---------------------------------------------------------------------------
extern "C" void kernel_launch(void* const* d_in, const int* in_sizes, int n_in,
                              void* d_out, int out_size, void* d_ws, size_t ws_size,
                              hipStream_t stream)
{
    const int*   idx  = (const int*)  d_in[0];
    const float* tok  = (const float*)d_in[1];
    const float* pos  = (const float*)d_in[2];
    const float* Wq   = (const float*)d_in[3];
    const float* Wk   = (const float*)d_in[4];
    const float* Wv   = (const float*)d_in[5];
    const float* Wo   = (const float*)d_in[6];
    const float* bo   = (const float*)d_in[7];
    const float* W1   = (const float*)d_in[8];
    const float* b1   = (const float*)d_in[9];
    const float* W2   = (const float*)d_in[10];
    const float* b2   = (const float*)d_in[11];
    const float* ln1g = (const float*)d_in[12];
    const float* ln1b = (const float*)d_in[13];
    const float* ln2g = (const float*)d_in[14];
    const float* ln2b = (const float*)d_in[15];
    const float* lnfg = (const float*)d_in[16];
    const float* lnfb = (const float*)d_in[17];
    const float* lmb  = (const float*)d_in[18];

    float* ws  = (float*)d_ws;
    float* x   = ws;                             // [2048,1024] residual stream
    float* hbf = ws + (size_t)2 * 1024 * 1024;   // LN output
    float* qb  = ws + (size_t)4 * 1024 * 1024;
    float* kb  = ws + (size_t)6 * 1024 * 1024;
    float* vb  = ws + (size_t)8 * 1024 * 1024;
    float* ob  = ws + (size_t)10 * 1024 * 1024;
    float* mid = qb;   // MLP intermediate [2048,4096] aliases dead q/k/v/o

    const dim3 blk(256);
    const dim3 gE (E_  / 64, MROWS / 64);   // (16,32)
    const dim3 gF (DFF_ / 64, MROWS / 64);  // (64,32)
    const dim3 gV (V_  / 64, MROWS / 64);   // (500,32)

    embed_k<<<MROWS, blk, 0, stream>>>(idx, tok, pos, x);

    for (int l = 0; l < L_; ++l) {
        const size_t wE = (size_t)l * E_ * E_;
        ln_k<<<MROWS, blk, 0, stream>>>(x, ln1g + l * E_, ln1b + l * E_, hbf);
        gemm_k<false,false,false,false><<<gE, blk, 0, stream>>>(
            hbf, Wq + wE, nullptr, nullptr, qb, MROWS, E_, E_);
        gemm_k<false,false,false,false><<<gE, blk, 0, stream>>>(
            hbf, Wk + wE, nullptr, nullptr, kb, MROWS, E_, E_);
        gemm_k<false,false,false,false><<<gE, blk, 0, stream>>>(
            hbf, Wv + wE, nullptr, nullptr, vb, MROWS, E_, E_);
        attn_k<<<dim3(T_ / 64, H_, B_), blk, 0, stream>>>(qb, kb, vb, ob);
        gemm_k<false,true,false,true><<<gE, blk, 0, stream>>>(
            ob, Wo + wE, bo + l * E_, x, x, MROWS, E_, E_);
        ln_k<<<MROWS, blk, 0, stream>>>(x, ln2g + l * E_, ln2b + l * E_, hbf);
        gemm_k<false,true,true,false><<<gF, blk, 0, stream>>>(
            hbf, W1 + (size_t)l * E_ * DFF_, b1 + l * DFF_, nullptr, mid,
            MROWS, DFF_, E_);
        gemm_k<false,true,false,true><<<gE, blk, 0, stream>>>(
            mid, W2 + (size_t)l * DFF_ * E_, b2 + l * E_, x, x, MROWS, E_, DFF_);
    }

    ln_k<<<MROWS, blk, 0, stream>>>(x, lnfg, lnfb, hbf);
    gemm_k<true,true,false,false><<<gV, blk, 0, stream>>>(
        hbf, tok, lmb, nullptr, (float*)d_out, MROWS, V_, E_);
}